// Round 10
// baseline (612.273 us; speedup 1.0000x reference)
//
#include <hip/hip_runtime.h>

// GCN 3-layer encoder: bucket-binned, phase-partitioned CSR + phased gather.
// Build: hist -> bucket scan -> bin (packed src<<9|dstLocal) -> per-bucket
// counting sort keyed (dstLocal, srcPhase) -> dst-sorted CSR + rpoff[8i+x]
// per-(row,phase) segment starts. Layer-2 gather sweeps 16K-src windows (2MB,
// L2-resident) with a mostly-resident grid; each wave owns M nodes with
// per-slot register partials accumulated across phases, reduced ONCE at end.
// Round-9 evidence: phasing drops FETCH 294->111MB; this removes its 7x
// edge re-scan + per-phase reduce overhead (307us -> instruction-bound).
// Aggregation on the narrower side (A@(H W) = (A@H)@W); norm folded as
// p = dinv*h ; agg = sum p[src] ; out = dinv*(agg + p_self).

#define G_GRAPHS 128
#define BK_SHIFT 9
#define BK 512        // dst nodes per bucket
#define NB_MAX 256    // max buckets
#define PH_SHIFT 14   // 16384-src window per phase (2MB of p2)
#define NPH 8         // phase slots (n <= 131072)
#define M_NODES 20    // nodes per wave in phased gather (acc = 80 VGPR)

// K1: global bucket histogram (grid-stride, LDS-staged)
__global__ void hist_kernel(const int* __restrict__ dst, int* __restrict__ bcnt,
                            int E, int nb) {
    __shared__ int h[NB_MAX];
    for (int t = threadIdx.x; t < NB_MAX; t += blockDim.x) h[t] = 0;
    __syncthreads();
    for (int e = blockIdx.x * blockDim.x + threadIdx.x; e < E; e += gridDim.x * blockDim.x)
        atomicAdd(&h[dst[e] >> BK_SHIFT], 1);
    __syncthreads();
    for (int t = threadIdx.x; t < nb; t += blockDim.x)
        if (h[t]) atomicAdd(&bcnt[t], h[t]);
}

// K2: single-block exclusive scan of bucket counts -> boff, cursor (nb <= 256)
__global__ void bscan_kernel(const int* __restrict__ bcnt, int* __restrict__ boff,
                             int* __restrict__ cursor, int nb) {
    __shared__ int tmp[NB_MAX];
    int t = threadIdx.x;
    int v = (t < nb) ? bcnt[t] : 0;
    tmp[t] = v;
    __syncthreads();
    for (int off = 1; off < NB_MAX; off <<= 1) {
        int u = (t >= off) ? tmp[t - off] : 0;
        __syncthreads();
        tmp[t] += u;
        __syncthreads();
    }
    if (t < nb) {
        int excl = tmp[t] - v;
        boff[t] = excl;
        cursor[t] = excl;
    }
    if (t == nb - 1) boff[nb] = tmp[t];
}

// K3: bin edges into buckets with per-(block,bucket) chunked reservation.
__global__ void bin_kernel(const int* __restrict__ src, const int* __restrict__ dst,
                           int* __restrict__ cursor, unsigned* __restrict__ bedge,
                           int E, int nb, int chunk) {
    __shared__ int lcnt[NB_MAX];
    __shared__ int lbase[NB_MAX];
    int start = blockIdx.x * chunk;
    int end = min(start + chunk, E);
    for (int t = threadIdx.x; t < NB_MAX; t += blockDim.x) lcnt[t] = 0;
    __syncthreads();
    for (int e = start + threadIdx.x; e < end; e += blockDim.x)
        atomicAdd(&lcnt[dst[e] >> BK_SHIFT], 1);
    __syncthreads();
    for (int t = threadIdx.x; t < nb; t += blockDim.x) {
        int c = lcnt[t];
        lbase[t] = c ? atomicAdd(&cursor[t], c) : 0;
    }
    __syncthreads();
    for (int t = threadIdx.x; t < NB_MAX; t += blockDim.x) lcnt[t] = 0;
    __syncthreads();
    for (int e = start + threadIdx.x; e < end; e += blockDim.x) {
        int d = dst[e];
        int bk = d >> BK_SHIFT;
        int pos = lbase[bk] + atomicAdd(&lcnt[bk], 1);
        bedge[pos] = ((unsigned)src[e] << BK_SHIFT) | (unsigned)(d & (BK - 1));
    }
}

// K4: per-bucket counting sort keyed (dstLocal, srcPhase) -> CSR + rpoff,
// fused with dinv and p1 = dinv*x (float4-padded).
__global__ __launch_bounds__(512) void sort_build(
    const unsigned* __restrict__ bedge, const int* __restrict__ boff,
    const float* __restrict__ x, int* __restrict__ csr, int* __restrict__ rpoff,
    float* __restrict__ dinv, float* __restrict__ p1, int n, int E) {
    __shared__ int hist[BK * NPH];   // 16 KB
    __shared__ int cur[BK * NPH];    // 16 KB
    __shared__ int tsum[512];
    int b = blockIdx.x;
    int beg = boff[b], end = boff[b + 1];
    int t = threadIdx.x;
    for (int q = t; q < BK * NPH; q += 512) hist[q] = 0;
    __syncthreads();
    for (int e = beg + t; e < end; e += 512) {
        unsigned u = bedge[e];
        int bin = ((u & (BK - 1)) << 3) | ((u >> BK_SHIFT) >> PH_SHIFT);
        atomicAdd(&hist[bin], 1);
    }
    __syncthreads();
    // thread t owns bins [8t, 8t+8) == node dl=t's 8 phase bins
    int loc[NPH];
    int sum = 0;
#pragma unroll
    for (int q = 0; q < NPH; ++q) { loc[q] = sum; sum += hist[t * NPH + q]; }
    tsum[t] = sum;
    __syncthreads();
    for (int off = 1; off < 512; off <<= 1) {
        int v = (t >= off) ? tsum[t - off] : 0;
        __syncthreads();
        tsum[t] += v;
        __syncthreads();
    }
    int carry = (t > 0) ? tsum[t - 1] : 0;  // exclusive over nodes
    int rowbase = beg + carry;
#pragma unroll
    for (int q = 0; q < NPH; ++q) cur[t * NPH + q] = rowbase + loc[q];
    int i = (b << BK_SHIFT) + t;
    if (i < n) {
#pragma unroll
        for (int q = 0; q < NPH; ++q) rpoff[(size_t)i * NPH + q] = rowbase + loc[q];
        float di = rsqrtf((float)sum + 1.0f);
        dinv[i] = di;
        *reinterpret_cast<float4*>(p1 + 4 * (size_t)i) =
            make_float4(di * x[3 * i + 0], di * x[3 * i + 1], di * x[3 * i + 2], 0.0f);
    }
    if (b == 0 && t == 0) rpoff[(size_t)n * NPH] = E;
    __syncthreads();
    for (int e = beg + t; e < end; e += 512) {
        unsigned u = bedge[e];
        int bin = ((u & (BK - 1)) << 3) | ((u >> BK_SHIFT) >> PH_SHIFT);
        int pos = atomicAdd(&cur[bin], 1);
        csr[pos] = (int)(u >> BK_SHIFT);
    }
}

// ---- Layers ---------------------------------------------------------------

// thread/node: gather float4 p1 rows, s = dinv*(sum + self), p2 = dinv*relu(s@W1+b1)
__global__ void layer1_fused(const int* __restrict__ csr, const int* __restrict__ rpoff,
                             const float* __restrict__ p1, const float* __restrict__ dinv,
                             const float* __restrict__ W1, const float* __restrict__ b1,
                             float* __restrict__ p2, int n) {
    __shared__ float w[96];
    __shared__ float bb[32];
    for (int t = threadIdx.x; t < 96; t += blockDim.x) w[t] = W1[t];
    for (int t = threadIdx.x; t < 32; t += blockDim.x) bb[t] = b1[t];
    __syncthreads();
    int i = blockIdx.x * blockDim.x + threadIdx.x;
    if (i >= n) return;
    int beg = rpoff[(size_t)i * NPH], end = rpoff[(size_t)i * NPH + NPH];
    float s0 = 0.f, s1 = 0.f, s2 = 0.f;
    for (int k = beg; k < end; ++k) {
        int s = csr[k];
        const float4 v = *reinterpret_cast<const float4*>(p1 + 4 * (size_t)s);
        s0 += v.x; s1 += v.y; s2 += v.z;
    }
    float d = dinv[i];
    const float4 sf = *reinterpret_cast<const float4*>(p1 + 4 * (size_t)i);
    s0 = d * (s0 + sf.x);
    s1 = d * (s1 + sf.y);
    s2 = d * (s2 + sf.z);
#pragma unroll
    for (int q = 0; q < 8; ++q) {
        float o[4];
#pragma unroll
        for (int c = 0; c < 4; ++c) {
            int j = q * 4 + c;
            float h = fmaf(s0, w[j], fmaf(s1, w[32 + j], fmaf(s2, w[64 + j], bb[j])));
            o[c] = d * fmaxf(h, 0.0f);
        }
        *reinterpret_cast<float4*>(p2 + 32 * (size_t)i + 4 * q) =
            make_float4(o[0], o[1], o[2], o[3]);
    }
}

// Phased wave-gather layer 2. One node per wave iteration (uniform trips);
// per-slot float4 partials persist in registers across phases (static unroll,
// M_NODES per wave); butterfly reduce + fused 32->64->2 transform ONCE per
// node in the epilogue. Per-phase __syncthreads keeps the block's waves in
// the same 2MB p2 window; grid ~resident so blocks sweep windows together.
__global__ __launch_bounds__(256, 4) void gather2_phased(
    const int* __restrict__ csr, const int* __restrict__ rpoff,
    const float* __restrict__ p2, const float* __restrict__ dinv,
    const float* __restrict__ W2, const float* __restrict__ b2,
    const float* __restrict__ W3, float* __restrict__ p3, int n) {
    __shared__ float w2[32 * 64];
    __shared__ float b2s[64];
    __shared__ float w3[128];
    for (int t = threadIdx.x; t < 32 * 64; t += 256) w2[t] = W2[t];
    if (threadIdx.x < 64)  b2s[threadIdx.x] = b2[threadIdx.x];
    if (threadIdx.x < 128) w3[threadIdx.x] = W3[threadIdx.x];
    __syncthreads();

    int lane = threadIdx.x & 63;
    int w = threadIdx.x >> 6;
    int base = (blockIdx.x * 4 + w) * M_NODES;
    int part = lane & 7;   // float4 part of the 32-float row
    int slot = lane >> 3;  // edge slot
    float4 acc[M_NODES];
#pragma unroll
    for (int jj = 0; jj < M_NODES; ++jj) acc[jj] = make_float4(0.f, 0.f, 0.f, 0.f);

    for (int x = 0; x < NPH; ++x) {
#pragma unroll
        for (int jj = 0; jj < M_NODES; ++jj) {
            int i = base + jj;
            if (i >= n) break;  // wave-uniform
            int rb = rpoff[(size_t)i * NPH + x];
            int re = rpoff[(size_t)i * NPH + x + 1];
            for (int k = rb + slot; k < re; k += 8) {
                int s = csr[k];
                const float4 v =
                    *reinterpret_cast<const float4*>(p2 + 32 * (size_t)s + 4 * part);
                acc[jj].x += v.x; acc[jj].y += v.y; acc[jj].z += v.z; acc[jj].w += v.w;
            }
        }
        __syncthreads();  // all resident waves advance to the next src window
    }

    // Epilogue: per node, reduce slots once, add self, transform, store.
#pragma unroll
    for (int jj = 0; jj < M_NODES; ++jj) {
        int i = base + jj;
        if (i >= n) break;
        float4 a = acc[jj];
#pragma unroll
        for (int m = 8; m <= 32; m <<= 1) {
            a.x += __shfl_xor(a.x, m, 64);
            a.y += __shfl_xor(a.y, m, 64);
            a.z += __shfl_xor(a.z, m, 64);
            a.w += __shfl_xor(a.w, m, 64);
        }
        float d = dinv[i];
        const float4 sv = *reinterpret_cast<const float4*>(p2 + 32 * (size_t)i + 4 * part);
        float4 sc;
        sc.x = d * (a.x + sv.x);
        sc.y = d * (a.y + sv.y);
        sc.z = d * (a.z + sv.z);
        sc.w = d * (a.w + sv.w);
        int jjj = lane;  // lane computes h2[lane]
        float h = b2s[jjj];
#pragma unroll
        for (int p = 0; p < 8; ++p) {
            float s0 = __shfl(sc.x, p, 64);
            float s1 = __shfl(sc.y, p, 64);
            float s2 = __shfl(sc.z, p, 64);
            float s3 = __shfl(sc.w, p, 64);
            h = fmaf(s0, w2[(4 * p + 0) * 64 + jjj], h);
            h = fmaf(s1, w2[(4 * p + 1) * 64 + jjj], h);
            h = fmaf(s2, w2[(4 * p + 2) * 64 + jjj], h);
            h = fmaf(s3, w2[(4 * p + 3) * 64 + jjj], h);
        }
        h = fmaxf(h, 0.0f);
        float a0 = h * w3[2 * jjj + 0];
        float a1 = h * w3[2 * jjj + 1];
#pragma unroll
        for (int m = 1; m < 64; m <<= 1) {
            a0 += __shfl_xor(a0, m, 64);
            a1 += __shfl_xor(a1, m, 64);
        }
        if (lane == 0) {
            p3[2 * (size_t)i + 0] = d * a0;
            p3[2 * (size_t)i + 1] = d * a1;
        }
    }
}

// thread/node: gather 2-wide rows, epilogue + mean-pool (LDS bins -> global atomics)
__global__ void layer3_pool(const int* __restrict__ csr, const int* __restrict__ rpoff,
                            const float* __restrict__ p3, const float* __restrict__ dinv,
                            const int* __restrict__ batch, const float* __restrict__ b3,
                            float* __restrict__ sums, float* __restrict__ cnt, int n) {
    __shared__ float ls[G_GRAPHS * 2];
    __shared__ float lc[G_GRAPHS];
    for (int t = threadIdx.x; t < G_GRAPHS * 2; t += blockDim.x) ls[t] = 0.0f;
    for (int t = threadIdx.x; t < G_GRAPHS; t += blockDim.x) lc[t] = 0.0f;
    __syncthreads();
    int i = blockIdx.x * blockDim.x + threadIdx.x;
    if (i < n) {
        int beg = rpoff[(size_t)i * NPH], end = rpoff[(size_t)i * NPH + NPH];
        float a0 = 0.f, a1 = 0.f;
        for (int k = beg; k < end; ++k) {
            int s = csr[k];
            a0 += p3[2 * (size_t)s + 0];
            a1 += p3[2 * (size_t)s + 1];
        }
        float d = dinv[i];
        float v0 = fmaf(d, a0 + p3[2 * (size_t)i + 0], b3[0]);
        float v1 = fmaf(d, a1 + p3[2 * (size_t)i + 1], b3[1]);
        int g = batch[i];
        atomicAdd(&ls[2 * g + 0], v0);
        atomicAdd(&ls[2 * g + 1], v1);
        atomicAdd(&lc[g], 1.0f);
    }
    __syncthreads();
    for (int g = threadIdx.x; g < G_GRAPHS; g += blockDim.x) {
        float c = lc[g];
        if (c != 0.0f) {
            atomicAdd(&sums[2 * g + 0], ls[2 * g + 0]);
            atomicAdd(&sums[2 * g + 1], ls[2 * g + 1]);
            atomicAdd(&cnt[g], c);
        }
    }
}

__global__ void finalize_kernel(const float* __restrict__ sums, const float* __restrict__ cnt,
                                float* __restrict__ out) {
    int g = threadIdx.x;
    if (g < G_GRAPHS) {
        float c = fmaxf(cnt[g], 1.0f);
        out[2 * g + 0] = sums[2 * g + 0] / c;
        out[2 * g + 1] = sums[2 * g + 1] / c;
    }
}

// ---- Launch ---------------------------------------------------------------

extern "C" void kernel_launch(void* const* d_in, const int* in_sizes, int n_in,
                              void* d_out, int out_size, void* d_ws, size_t ws_size,
                              hipStream_t stream) {
    const float* x     = (const float*)d_in[0];
    const int*   ei    = (const int*)d_in[1];
    const int*   batch = (const int*)d_in[2];
    const float* W1    = (const float*)d_in[3];
    const float* b1    = (const float*)d_in[4];
    const float* W2    = (const float*)d_in[5];
    const float* b2    = (const float*)d_in[6];
    const float* W3    = (const float*)d_in[7];
    const float* b3    = (const float*)d_in[8];
    float* out = (float*)d_out;

    const int n = in_sizes[0] / 3;
    const int E = in_sizes[1] / 2;
    const int* src = ei;
    const int* dst = ei + E;
    const int nb = (n + BK - 1) >> BK_SHIFT;

    // Workspace layout (4-byte words). Zeroed prefix: bcnt + sums + cnt.
    int* w = (int*)d_ws;
    size_t off = 0;
    auto take = [&](size_t words) { size_t o = off; off = (off + words + 3) & ~(size_t)3; return o; };
    int*      bcnt   = w + take(512);
    float*    sums   = (float*)(w + take(2 * G_GRAPHS));
    float*    cnt    = (float*)(w + take(G_GRAPHS));
    int*      boff   = w + take(NB_MAX + 1);
    int*      cursor = w + take(NB_MAX);
    int*      csr    = w + take(E);
    int*      rpoff  = w + take((size_t)n * NPH + 1);
    float*    dinv   = (float*)(w + take(n));
    float*    p1     = (float*)(w + take(4 * (size_t)n));
    off = (off + 31) & ~(size_t)31;  // align p2 rows to 128B
    float*    p2     = (float*)(w + take(32 * (size_t)n));
    float*    p3     = (float*)(w + take(2 * (size_t)n));
    // bedge aliases p2 (dead before layer1 writes p2). 32n >= E here; else tail.
    unsigned* bedge  = (32 * (size_t)n >= (size_t)E) ? (unsigned*)p2 : (unsigned*)(w + take(E));

    hipMemsetAsync(d_ws, 0, 896 * 4, stream);

    const int B = 256;
    const int gridN = (n + B - 1) / B;
    const int BINB = 1024;
    const int chunk = (E + BINB - 1) / BINB;
    const int grid2 = (n + 4 * M_NODES - 1) / (4 * M_NODES);  // 1250 for n=100000

    hist_kernel<<<BINB, B, 0, stream>>>(dst, bcnt, E, nb);
    bscan_kernel<<<1, NB_MAX, 0, stream>>>(bcnt, boff, cursor, nb);
    bin_kernel<<<BINB, B, 0, stream>>>(src, dst, cursor, bedge, E, nb, chunk);
    sort_build<<<nb, BK, 0, stream>>>(bedge, boff, x, csr, rpoff, dinv, p1, n, E);
    layer1_fused<<<gridN, B, 0, stream>>>(csr, rpoff, p1, dinv, W1, b1, p2, n);
    gather2_phased<<<grid2, 256, 0, stream>>>(csr, rpoff, p2, dinv, W2, b2, W3, p3, n);
    layer3_pool<<<gridN, B, 0, stream>>>(csr, rpoff, p3, dinv, batch, b3, sums, cnt, n);
    finalize_kernel<<<1, 128, 0, stream>>>(sums, cnt, out);
}

// Round 11
// 538.447 us; speedup vs baseline: 1.1371x; 1.1371x over previous
//
#include <hip/hip_runtime.h>

// GCN 3-layer encoder: bucket-binned, phase-partitioned CSR + phased gather.
// Build: hist -> bucket scan -> bin (packed src<<9|dstLocal) -> per-bucket
// counting sort keyed (dstLocal, srcPhase) -> dst-sorted CSR + rpoff[8i+x]
// per-(row,phase) segment starts. Layer-2 gather sweeps 16K-src windows (2MB,
// L2-resident): each wave owns M_NODES=16 nodes; per-slot float4 partials live
// in REGISTERS across phases (full static unroll, NO break inside unrolled
// loops -- round-10 evidence: break blocked unroll -> acc spilled to scratch,
// WRITE_SIZE 78MB). Butterfly reduce + fused 32->64->2 transform once/node.
// Aggregation on the narrower side (A@(H W) = (A@H)@W); norm folded as
// p = dinv*h ; agg = sum p[src] ; out = dinv*(agg + p_self).

#define G_GRAPHS 128
#define BK_SHIFT 9
#define BK 512        // dst nodes per bucket
#define NB_MAX 256    // max buckets
#define PH_SHIFT 14   // 16384-src window per phase (2MB of p2)
#define NPH 8         // phase slots (n <= 131072)
#define M_NODES 16    // nodes per wave (acc = 64 VGPR, fits 128-cap)

// K1: global bucket histogram (grid-stride, LDS-staged)
__global__ void hist_kernel(const int* __restrict__ dst, int* __restrict__ bcnt,
                            int E, int nb) {
    __shared__ int h[NB_MAX];
    for (int t = threadIdx.x; t < NB_MAX; t += blockDim.x) h[t] = 0;
    __syncthreads();
    for (int e = blockIdx.x * blockDim.x + threadIdx.x; e < E; e += gridDim.x * blockDim.x)
        atomicAdd(&h[dst[e] >> BK_SHIFT], 1);
    __syncthreads();
    for (int t = threadIdx.x; t < nb; t += blockDim.x)
        if (h[t]) atomicAdd(&bcnt[t], h[t]);
}

// K2: single-block exclusive scan of bucket counts -> boff, cursor (nb <= 256)
__global__ void bscan_kernel(const int* __restrict__ bcnt, int* __restrict__ boff,
                             int* __restrict__ cursor, int nb) {
    __shared__ int tmp[NB_MAX];
    int t = threadIdx.x;
    int v = (t < nb) ? bcnt[t] : 0;
    tmp[t] = v;
    __syncthreads();
    for (int off = 1; off < NB_MAX; off <<= 1) {
        int u = (t >= off) ? tmp[t - off] : 0;
        __syncthreads();
        tmp[t] += u;
        __syncthreads();
    }
    if (t < nb) {
        int excl = tmp[t] - v;
        boff[t] = excl;
        cursor[t] = excl;
    }
    if (t == nb - 1) boff[nb] = tmp[t];
}

// K3: bin edges into buckets with per-(block,bucket) chunked reservation.
__global__ void bin_kernel(const int* __restrict__ src, const int* __restrict__ dst,
                           int* __restrict__ cursor, unsigned* __restrict__ bedge,
                           int E, int nb, int chunk) {
    __shared__ int lcnt[NB_MAX];
    __shared__ int lbase[NB_MAX];
    int start = blockIdx.x * chunk;
    int end = min(start + chunk, E);
    for (int t = threadIdx.x; t < NB_MAX; t += blockDim.x) lcnt[t] = 0;
    __syncthreads();
    for (int e = start + threadIdx.x; e < end; e += blockDim.x)
        atomicAdd(&lcnt[dst[e] >> BK_SHIFT], 1);
    __syncthreads();
    for (int t = threadIdx.x; t < nb; t += blockDim.x) {
        int c = lcnt[t];
        lbase[t] = c ? atomicAdd(&cursor[t], c) : 0;
    }
    __syncthreads();
    for (int t = threadIdx.x; t < NB_MAX; t += blockDim.x) lcnt[t] = 0;
    __syncthreads();
    for (int e = start + threadIdx.x; e < end; e += blockDim.x) {
        int d = dst[e];
        int bk = d >> BK_SHIFT;
        int pos = lbase[bk] + atomicAdd(&lcnt[bk], 1);
        bedge[pos] = ((unsigned)src[e] << BK_SHIFT) | (unsigned)(d & (BK - 1));
    }
}

// K4: per-bucket counting sort keyed (dstLocal, srcPhase) -> CSR + rpoff,
// fused with dinv and p1 = dinv*x (float4-padded).
__global__ __launch_bounds__(512) void sort_build(
    const unsigned* __restrict__ bedge, const int* __restrict__ boff,
    const float* __restrict__ x, int* __restrict__ csr, int* __restrict__ rpoff,
    float* __restrict__ dinv, float* __restrict__ p1, int n, int E) {
    __shared__ int hist[BK * NPH];   // 16 KB
    __shared__ int cur[BK * NPH];    // 16 KB
    __shared__ int tsum[512];
    int b = blockIdx.x;
    int beg = boff[b], end = boff[b + 1];
    int t = threadIdx.x;
    for (int q = t; q < BK * NPH; q += 512) hist[q] = 0;
    __syncthreads();
    for (int e = beg + t; e < end; e += 512) {
        unsigned u = bedge[e];
        int bin = ((u & (BK - 1)) << 3) | ((u >> BK_SHIFT) >> PH_SHIFT);
        atomicAdd(&hist[bin], 1);
    }
    __syncthreads();
    // thread t owns bins [8t, 8t+8) == node dl=t's 8 phase bins
    int loc[NPH];
    int sum = 0;
#pragma unroll
    for (int q = 0; q < NPH; ++q) { loc[q] = sum; sum += hist[t * NPH + q]; }
    tsum[t] = sum;
    __syncthreads();
    for (int off = 1; off < 512; off <<= 1) {
        int v = (t >= off) ? tsum[t - off] : 0;
        __syncthreads();
        tsum[t] += v;
        __syncthreads();
    }
    int carry = (t > 0) ? tsum[t - 1] : 0;  // exclusive over nodes
    int rowbase = beg + carry;
#pragma unroll
    for (int q = 0; q < NPH; ++q) cur[t * NPH + q] = rowbase + loc[q];
    int i = (b << BK_SHIFT) + t;
    if (i < n) {
#pragma unroll
        for (int q = 0; q < NPH; ++q) rpoff[(size_t)i * NPH + q] = rowbase + loc[q];
        float di = rsqrtf((float)sum + 1.0f);
        dinv[i] = di;
        *reinterpret_cast<float4*>(p1 + 4 * (size_t)i) =
            make_float4(di * x[3 * i + 0], di * x[3 * i + 1], di * x[3 * i + 2], 0.0f);
    }
    if (b == 0 && t == 0) rpoff[(size_t)n * NPH] = E;
    __syncthreads();
    for (int e = beg + t; e < end; e += 512) {
        unsigned u = bedge[e];
        int bin = ((u & (BK - 1)) << 3) | ((u >> BK_SHIFT) >> PH_SHIFT);
        int pos = atomicAdd(&cur[bin], 1);
        csr[pos] = (int)(u >> BK_SHIFT);
    }
}

// ---- Layers ---------------------------------------------------------------

// thread/node: gather float4 p1 rows, s = dinv*(sum + self), p2 = dinv*relu(s@W1+b1)
__global__ void layer1_fused(const int* __restrict__ csr, const int* __restrict__ rpoff,
                             const float* __restrict__ p1, const float* __restrict__ dinv,
                             const float* __restrict__ W1, const float* __restrict__ b1,
                             float* __restrict__ p2, int n) {
    __shared__ float w[96];
    __shared__ float bb[32];
    for (int t = threadIdx.x; t < 96; t += blockDim.x) w[t] = W1[t];
    for (int t = threadIdx.x; t < 32; t += blockDim.x) bb[t] = b1[t];
    __syncthreads();
    int i = blockIdx.x * blockDim.x + threadIdx.x;
    if (i >= n) return;
    int beg = rpoff[(size_t)i * NPH], end = rpoff[(size_t)i * NPH + NPH];
    float s0 = 0.f, s1 = 0.f, s2 = 0.f;
    for (int k = beg; k < end; ++k) {
        int s = csr[k];
        const float4 v = *reinterpret_cast<const float4*>(p1 + 4 * (size_t)s);
        s0 += v.x; s1 += v.y; s2 += v.z;
    }
    float d = dinv[i];
    const float4 sf = *reinterpret_cast<const float4*>(p1 + 4 * (size_t)i);
    s0 = d * (s0 + sf.x);
    s1 = d * (s1 + sf.y);
    s2 = d * (s2 + sf.z);
#pragma unroll
    for (int q = 0; q < 8; ++q) {
        float o[4];
#pragma unroll
        for (int c = 0; c < 4; ++c) {
            int j = q * 4 + c;
            float h = fmaf(s0, w[j], fmaf(s1, w[32 + j], fmaf(s2, w[64 + j], bb[j])));
            o[c] = d * fmaxf(h, 0.0f);
        }
        *reinterpret_cast<float4*>(p2 + 32 * (size_t)i + 4 * q) =
            make_float4(o[0], o[1], o[2], o[3]);
    }
}

// Phased wave-gather layer 2. Each wave owns M_NODES=16 nodes; per-slot
// float4 partials persist in registers across phases. All loops over nodes
// have CONSTANT bounds and per-iteration guards (no break) so the unroll is
// full and acc indices are compile-time constants (rule: dynamic-indexed
// ext_vector arrays go to scratch). Reduce + transform once per node at end.
__global__ __launch_bounds__(256, 4) void gather2_phased(
    const int* __restrict__ csr, const int* __restrict__ rpoff,
    const float* __restrict__ p2, const float* __restrict__ dinv,
    const float* __restrict__ W2, const float* __restrict__ b2,
    const float* __restrict__ W3, float* __restrict__ p3, int n) {
    __shared__ float w2[32 * 64];
    __shared__ float b2s[64];
    __shared__ float w3[128];
    for (int t = threadIdx.x; t < 32 * 64; t += 256) w2[t] = W2[t];
    if (threadIdx.x < 64)  b2s[threadIdx.x] = b2[threadIdx.x];
    if (threadIdx.x < 128) w3[threadIdx.x] = W3[threadIdx.x];
    __syncthreads();

    int lane = threadIdx.x & 63;
    int w = threadIdx.x >> 6;
    int base = (blockIdx.x * 4 + w) * M_NODES;
    int part = lane & 7;   // float4 part of the 32-float row
    int slot = lane >> 3;  // edge slot
    float4 acc[M_NODES];
#pragma unroll
    for (int jj = 0; jj < M_NODES; ++jj) acc[jj] = make_float4(0.f, 0.f, 0.f, 0.f);

    for (int x = 0; x < NPH; ++x) {
#pragma unroll
        for (int jj = 0; jj < M_NODES; ++jj) {
            int i = base + jj;
            if (i < n) {
                int rb = rpoff[(size_t)i * NPH + x];
                int re = rpoff[(size_t)i * NPH + x + 1];
                for (int k = rb + slot; k < re; k += 8) {
                    int s = csr[k];
                    const float4 v =
                        *reinterpret_cast<const float4*>(p2 + 32 * (size_t)s + 4 * part);
                    acc[jj].x += v.x; acc[jj].y += v.y;
                    acc[jj].z += v.z; acc[jj].w += v.w;
                }
            }
        }
        __syncthreads();  // all resident waves advance to the next src window
    }

    // Epilogue: per node, reduce slots once, add self, transform, store.
#pragma unroll
    for (int jj = 0; jj < M_NODES; ++jj) {
        int i = base + jj;
        if (i < n) {
            float4 a = acc[jj];
#pragma unroll
            for (int m = 8; m <= 32; m <<= 1) {
                a.x += __shfl_xor(a.x, m, 64);
                a.y += __shfl_xor(a.y, m, 64);
                a.z += __shfl_xor(a.z, m, 64);
                a.w += __shfl_xor(a.w, m, 64);
            }
            float d = dinv[i];
            const float4 sv =
                *reinterpret_cast<const float4*>(p2 + 32 * (size_t)i + 4 * part);
            float4 sc;
            sc.x = d * (a.x + sv.x);
            sc.y = d * (a.y + sv.y);
            sc.z = d * (a.z + sv.z);
            sc.w = d * (a.w + sv.w);
            int jjj = lane;  // lane computes h2[lane]
            float h = b2s[jjj];
#pragma unroll
            for (int p = 0; p < 8; ++p) {
                float s0 = __shfl(sc.x, p, 64);
                float s1 = __shfl(sc.y, p, 64);
                float s2 = __shfl(sc.z, p, 64);
                float s3 = __shfl(sc.w, p, 64);
                h = fmaf(s0, w2[(4 * p + 0) * 64 + jjj], h);
                h = fmaf(s1, w2[(4 * p + 1) * 64 + jjj], h);
                h = fmaf(s2, w2[(4 * p + 2) * 64 + jjj], h);
                h = fmaf(s3, w2[(4 * p + 3) * 64 + jjj], h);
            }
            h = fmaxf(h, 0.0f);
            float a0 = h * w3[2 * jjj + 0];
            float a1 = h * w3[2 * jjj + 1];
#pragma unroll
            for (int m = 1; m < 64; m <<= 1) {
                a0 += __shfl_xor(a0, m, 64);
                a1 += __shfl_xor(a1, m, 64);
            }
            if (lane == 0) {
                p3[2 * (size_t)i + 0] = d * a0;
                p3[2 * (size_t)i + 1] = d * a1;
            }
        }
    }
}

// thread/node: gather 2-wide rows, epilogue + mean-pool (LDS bins -> global atomics)
__global__ void layer3_pool(const int* __restrict__ csr, const int* __restrict__ rpoff,
                            const float* __restrict__ p3, const float* __restrict__ dinv,
                            const int* __restrict__ batch, const float* __restrict__ b3,
                            float* __restrict__ sums, float* __restrict__ cnt, int n) {
    __shared__ float ls[G_GRAPHS * 2];
    __shared__ float lc[G_GRAPHS];
    for (int t = threadIdx.x; t < G_GRAPHS * 2; t += blockDim.x) ls[t] = 0.0f;
    for (int t = threadIdx.x; t < G_GRAPHS; t += blockDim.x) lc[t] = 0.0f;
    __syncthreads();
    int i = blockIdx.x * blockDim.x + threadIdx.x;
    if (i < n) {
        int beg = rpoff[(size_t)i * NPH], end = rpoff[(size_t)i * NPH + NPH];
        float a0 = 0.f, a1 = 0.f;
        for (int k = beg; k < end; ++k) {
            int s = csr[k];
            a0 += p3[2 * (size_t)s + 0];
            a1 += p3[2 * (size_t)s + 1];
        }
        float d = dinv[i];
        float v0 = fmaf(d, a0 + p3[2 * (size_t)i + 0], b3[0]);
        float v1 = fmaf(d, a1 + p3[2 * (size_t)i + 1], b3[1]);
        int g = batch[i];
        atomicAdd(&ls[2 * g + 0], v0);
        atomicAdd(&ls[2 * g + 1], v1);
        atomicAdd(&lc[g], 1.0f);
    }
    __syncthreads();
    for (int g = threadIdx.x; g < G_GRAPHS; g += blockDim.x) {
        float c = lc[g];
        if (c != 0.0f) {
            atomicAdd(&sums[2 * g + 0], ls[2 * g + 0]);
            atomicAdd(&sums[2 * g + 1], ls[2 * g + 1]);
            atomicAdd(&cnt[g], c);
        }
    }
}

__global__ void finalize_kernel(const float* __restrict__ sums, const float* __restrict__ cnt,
                                float* __restrict__ out) {
    int g = threadIdx.x;
    if (g < G_GRAPHS) {
        float c = fmaxf(cnt[g], 1.0f);
        out[2 * g + 0] = sums[2 * g + 0] / c;
        out[2 * g + 1] = sums[2 * g + 1] / c;
    }
}

// ---- Launch ---------------------------------------------------------------

extern "C" void kernel_launch(void* const* d_in, const int* in_sizes, int n_in,
                              void* d_out, int out_size, void* d_ws, size_t ws_size,
                              hipStream_t stream) {
    const float* x     = (const float*)d_in[0];
    const int*   ei    = (const int*)d_in[1];
    const int*   batch = (const int*)d_in[2];
    const float* W1    = (const float*)d_in[3];
    const float* b1    = (const float*)d_in[4];
    const float* W2    = (const float*)d_in[5];
    const float* b2    = (const float*)d_in[6];
    const float* W3    = (const float*)d_in[7];
    const float* b3    = (const float*)d_in[8];
    float* out = (float*)d_out;

    const int n = in_sizes[0] / 3;
    const int E = in_sizes[1] / 2;
    const int* src = ei;
    const int* dst = ei + E;
    const int nb = (n + BK - 1) >> BK_SHIFT;

    // Workspace layout (4-byte words). Zeroed prefix: bcnt + sums + cnt.
    int* w = (int*)d_ws;
    size_t off = 0;
    auto take = [&](size_t words) { size_t o = off; off = (off + words + 3) & ~(size_t)3; return o; };
    int*      bcnt   = w + take(512);
    float*    sums   = (float*)(w + take(2 * G_GRAPHS));
    float*    cnt    = (float*)(w + take(G_GRAPHS));
    int*      boff   = w + take(NB_MAX + 1);
    int*      cursor = w + take(NB_MAX);
    int*      csr    = w + take(E);
    int*      rpoff  = w + take((size_t)n * NPH + 1);
    float*    dinv   = (float*)(w + take(n));
    float*    p1     = (float*)(w + take(4 * (size_t)n));
    off = (off + 31) & ~(size_t)31;  // align p2 rows to 128B
    float*    p2     = (float*)(w + take(32 * (size_t)n));
    float*    p3     = (float*)(w + take(2 * (size_t)n));
    // bedge aliases p2 (dead before layer1 writes p2). 32n >= E here; else tail.
    unsigned* bedge  = (32 * (size_t)n >= (size_t)E) ? (unsigned*)p2 : (unsigned*)(w + take(E));

    hipMemsetAsync(d_ws, 0, 896 * 4, stream);

    const int B = 256;
    const int gridN = (n + B - 1) / B;
    const int BINB = 1024;
    const int chunk = (E + BINB - 1) / BINB;
    const int grid2 = (n + 4 * M_NODES - 1) / (4 * M_NODES);  // 1563 for n=100000

    hist_kernel<<<BINB, B, 0, stream>>>(dst, bcnt, E, nb);
    bscan_kernel<<<1, NB_MAX, 0, stream>>>(bcnt, boff, cursor, nb);
    bin_kernel<<<BINB, B, 0, stream>>>(src, dst, cursor, bedge, E, nb, chunk);
    sort_build<<<nb, BK, 0, stream>>>(bedge, boff, x, csr, rpoff, dinv, p1, n, E);
    layer1_fused<<<gridN, B, 0, stream>>>(csr, rpoff, p1, dinv, W1, b1, p2, n);
    gather2_phased<<<grid2, 256, 0, stream>>>(csr, rpoff, p2, dinv, W2, b2, W3, p3, n);
    layer3_pool<<<gridN, B, 0, stream>>>(csr, rpoff, p3, dinv, batch, b3, sums, cnt, n);
    finalize_kernel<<<1, 128, 0, stream>>>(sums, cnt, out);
}